// Round 22
// baseline (162.456 us; speedup 1.0000x reference)
//
#include <hip/hip_runtime.h>
#include <hip/hip_fp16.h>
#include <stdint.h>

#define T_LEN 1460
#define NBT (256 * T_LEN)          // 373,760 (b,t) records
#define NREC (NBT * 16)            // 5,980,160 chain records
#define CSZ 20                     // steps per chunk; 1460 = 73 * 20
#define PCH (CSZ * 1024)           // param chunk: 20 x (4 planes x 256B) = 20480
#define VCH (CSZ * 64)             // V chunk: 20 x 4 basins x 16B = 1280
#define Q1CH (CSZ * 512)           // {qf,qu} chunk: 20 x 64 x 8B = 10240
#define Q2CH (CSZ * 256)           // qu_out chunk: 20 x 64 x 4B = 5120

typedef __attribute__((address_space(3))) char lds_c;
typedef __attribute__((address_space(1))) const char g_c;

__device__ __forceinline__ float sigmf(float x) {
    float e = __builtin_amdgcn_exp2f(-1.44269504f * x);
    return __builtin_amdgcn_rcpf(1.0f + e);
}
__device__ __forceinline__ float rcpf(float x) { return __builtin_amdgcn_rcpf(x); }

__device__ __forceinline__ uint32_t pkh2(float a, float b) {
    __half2 h = __floats2half2_rn(a, b);
    union { __half2 h; uint32_t u; } c; c.h = h; return c.u;
}
__device__ __forceinline__ float2 h2f(uint32_t u) {
    union { uint32_t u; __half2 h; } c; c.u = u;
    return __half22float2(c.h);
}

// sum over each 16-lane row via full-rate DPP adds; result broadcast
__device__ __forceinline__ float row_sum16(float x) {
    x += __int_as_float(__builtin_amdgcn_update_dpp(0, __float_as_int(x), 0xB1, 0xF, 0xF, true));
    x += __int_as_float(__builtin_amdgcn_update_dpp(0, __float_as_int(x), 0x4E, 0xF, 0xF, true));
    x += __int_as_float(__builtin_amdgcn_update_dpp(0, __float_as_int(x), 0x141, 0xF, 0xF, true));
    x += __int_as_float(__builtin_amdgcn_update_dpp(0, __float_as_int(x), 0x140, 0xF, 0xF, true));
    return x;
}

// ---------------------------------------------------------------------------
// Kernel A: f16-packed parameter mapping, PLANAR output.
// Plane p (u32 per (bt,m)): 0:{sm,f_thr} 1:{sumax,beta} 2:{perc,rkf} 3:{rki,rkb}
// V per (b,t): float4 {sn, lpq, 0.9*pet, 0}.
// ---------------------------------------------------------------------------
__global__ __launch_bounds__(256) void shm_param_kernel(
    const float* __restrict__ xc, const float* __restrict__ lo,
    uint32_t* __restrict__ R2, float* __restrict__ V)
{
    const int tid = blockIdx.x * 256 + threadIdx.x;
    const int m  = tid & 15;
    const int bt = tid >> 4;

    const float* lr = lo + (size_t)bt * 128 + m;
    const float r0 = lr[0],   r1 = lr[16],  r2 = lr[32],  r3 = lr[48];
    const float r4 = lr[64],  r5 = lr[80],  r6 = lr[96],  r7 = lr[112];

    const float* xp = xc + (size_t)bt * 3;
    const float prec = xp[0], pet = xp[1], temp = xp[2];
    const bool frozen = (temp < 0.f);
    const float tpos = frozen ? 0.f : temp;

    const float dd    = 10.f * sigmf(r0);
    const float sm    = tpos * dd;
    const float f_thr = fmaf(sigmf(r1), 50.f, 10.f);
    const float sumax = fmaf(sigmf(r2), 680.f, 20.f);
    const float beta  = fmaf(sigmf(r3), 5.f, 1.f);
    const float perc  = sigmf(r4);
    const float rkf   = rcpf(fmaf(sigmf(r5), 19.f, 1.f));
    const float rki   = rcpf(fmaf(sigmf(r6), 99.f, 1.f));
    const float rkb   = rcpf(fmaf(sigmf(r7), 990.f, 10.f));

    R2[tid]            = pkh2(sm, f_thr);
    R2[NREC + tid]     = pkh2(sumax, beta);
    R2[2 * NREC + tid] = pkh2(perc, rkf);
    R2[3 * NREC + tid] = pkh2(rki, rkb);
    if (m == 0)
        *(float4*)(V + (size_t)bt * 4) =
            make_float4(frozen ? prec : 0.f, frozen ? 0.f : prec, 0.9f * pet, 0.f);
}

// ---------------------------------------------------------------------------
// Kernel B: 3-stage wave pipeline (r21 structure), planar conflict-free LDS.
//   w0: ss-chain chunk r -> q1{qf,qu}; + all DMA issuing (chunk r+1, 82x DMA4)
//   w1: su-chain chunk r-1: ULOAD (60 conflict-free b32) then register chain
//   w2: linear reservoirs + 16-mean + store, chunk r-2
// Step LDS layout: [p0 256B][p1 256B][p2 256B][p3 256B]; read at lane*4.
// Rings identical to r21 (passed): pring ring-4, vring/q1 ring-3, q2 ring-2.
// ---------------------------------------------------------------------------
__global__ __launch_bounds__(192, 1) void shm_serial_kernel(
    const char* __restrict__ R2,
    const char* __restrict__ V,
    float* __restrict__ out)
{
    __shared__ __align__(16) char pring[4 * PCH];    // 81920
    __shared__ __align__(16) char vring[3 * VCH];    //  3840
    __shared__ __align__(16) char q1[3 * Q1CH];      // 30720
    __shared__ __align__(16) char q2[2 * Q2CH];      // 10240

    const int lane = threadIdx.x & 63;
    const int wid  = threadIdx.x >> 6;
    const int m = lane & 15;
    const int bbase = blockIdx.x * 4;
    const int b = bbase + (lane >> 4);
    float* op = out + (size_t)b * T_LEN;

    lds_c* plp = (lds_c*)pring;
    lds_c* plv = (lds_c*)vring;
    const int voff = (lane >> 4) << 4;   // basin offset within V step-record

    // per-wave state
    float ss = 0.f;                       // w0
    float su = 5.f;                       // w1
    float sf = 1.f, si = 10.f, sb = 15.f, qk = 0.f;   // w2

    // DMA source pointers (w0): per-lane offset within each plane
    const size_t boff = (((size_t)b * T_LEN) * 16 + m) * 4;
    const char* pR0 = R2 + boff;
    const char* pR1 = R2 + (size_t)NREC * 4 + boff;
    const char* pR2p = R2 + (size_t)NREC * 8 + boff;
    const char* pR3 = R2 + (size_t)NREC * 12 + boff;
    const char* pV1 = V + ((size_t)(bbase + (lane & 3)) * T_LEN + (lane >> 2)) * 16;
    const char* pV2 = V + ((size_t)(bbase + (lane & 3)) * T_LEN + 16 + (lane >> 2)) * 16;

#define FOR20(X) X(0) X(1) X(2) X(3) X(4) X(5) X(6) X(7) X(8) X(9) \
                 X(10) X(11) X(12) X(13) X(14) X(15) X(16) X(17) X(18) X(19)

#define ISSUECHUNK(wbp, wbv) {                                                \
    _Pragma("unroll") for (int J = 0; J < 20; ++J) {                          \
        __builtin_amdgcn_global_load_lds((g_c*)(pR0 + J * 64),  plp + (wbp) + J * 1024,       4, 0, 0); \
        __builtin_amdgcn_global_load_lds((g_c*)(pR1 + J * 64),  plp + (wbp) + J * 1024 + 256, 4, 0, 0); \
        __builtin_amdgcn_global_load_lds((g_c*)(pR2p + J * 64), plp + (wbp) + J * 1024 + 512, 4, 0, 0); \
        __builtin_amdgcn_global_load_lds((g_c*)(pR3 + J * 64),  plp + (wbp) + J * 1024 + 768, 4, 0, 0); \
    }                                                                         \
    __builtin_amdgcn_global_load_lds((g_c*)pV1, plv + (wbv), 16, 0, 0);       \
    if (lane < 16)                                                            \
        __builtin_amdgcn_global_load_lds((g_c*)pV2, plv + (wbv) + 1024, 16, 0, 0); \
    pR0 += 1280; pR1 += 1280; pR2p += 1280; pR3 += 1280;                      \
    pV1 += 320; pV2 += 320; }

// w0: ss-chain step (chunk r); plane0 read at lane*4 (conflict-free)
#define SSTEP(J) {                                                            \
    const float2 p0 = h2f(*(const uint32_t*)(pring + sp0 + (J) * 1024 + lane * 4)); \
    const float2 snl = *(const float2*)(vring + sv0 + (J) * 64 + voff);       \
    const float qs_out = fminf(ss, p0.x);                                     \
    ss = (ss - qs_out) + snl.x;                                               \
    const float qsp = qs_out + snl.y;                                         \
    const float qf_ = fmaxf(0.f, qsp - p0.y);                                 \
    const float qu_ = fminf(qsp, p0.y);                                       \
    *(float2*)(q1 + sq10 + (J) * 512 + lane * 8) = make_float2(qf_, qu_); }

// w1: load phase (all independent, conflict-free)
#define ULOAD(J)                                                              \
    const uint32_t UY##J = *(const uint32_t*)(pring + sp1 + (J) * 1024 + 256 + lane * 4); \
    const float UE##J = *(const float*)(vring + sv1 + (J) * 64 + voff + 8);   \
    const float UQ##J = *(const float*)(q1 + sq11 + (J) * 512 + lane * 8 + 4);

// w1: register-only su-chain step (micro-optimized: su+qu in parallel with
// log/exp; k1=1-e_i off-chain; select via cndmask)
#define UCHAIN(J) {                                                           \
    const float2 p1 = h2f(UY##J);         /* sumax, beta */                   \
    const float sumax = p1.x, beta = p1.y, et09 = UE##J, qu_in = UQ##J;       \
    const float inv = rcpf(sumax);                                            \
    const float pwp = 0.8f * sumax;                                           \
    const float k1 = 1.f - et09 * inv;                                        \
    const float spq = su + qu_in;                                             \
    const float u = su * inv;                                                 \
    const float psi = __builtin_amdgcn_exp2f(beta * __builtin_amdgcn_logf(u));\
    const float su_t = fmaf(-qu_in, psi, spq);                                \
    const float su2 = fminf(su_t, sumax);                                     \
    const float ovf = fmaxf(0.f, su_t - sumax);                               \
    const float qu_out = fmaf(qu_in, psi, ovf);                               \
    const float a_ = su2 * k1;                                                \
    const float b_ = su2 - et09;                                              \
    su = fmaxf(0.f, (su2 <= pwp) ? a_ : b_);                                  \
    *(float*)(q2 + sq21 + (J) * 256 + lane * 4) = qu_out; }

// w2: linear step (chunk r-2); planes 2,3 at lane*4 (conflict-free)
#define LSTEP(J, tt) {                                                        \
    const float2 p2 = h2f(*(const uint32_t*)(pring + sp2 + (J) * 1024 + 512 + lane * 4)); \
    const float2 p3 = h2f(*(const uint32_t*)(pring + sp2 + (J) * 1024 + 768 + lane * 4)); \
    const float qf_in = *(const float*)(q1 + sq12 + (J) * 512 + lane * 8);    \
    const float quo = *(const float*)(q2 + sq22 + (J) * 256 + lane * 4);      \
    sf += qf_in; const float qf_out = sf * p2.y; sf -= qf_out;                \
    const float qi_in = quo * p2.x;                                           \
    si += qi_in; const float qi_out = si * p3.x; si -= qi_out;                \
    sb += (quo - qi_in); const float qb_out = sb * p3.y; sb -= qb_out;        \
    const float q_ = row_sum16(qf_out + qi_out + qb_out) * 0.0625f;           \
    qk = (m == ((tt) & 15)) ? q_ : qk;                                        \
    if (((tt) & 15) == 15) op[((tt) & ~15) + m] = qk; }

    // prologue: w0 issues chunk 0 into slot 0
    if (wid == 0) ISSUECHUNK(0, 0)
    __syncthreads();

    for (int r = 0; r <= 74; ++r) {
        if (wid == 0) {
            if (r <= 71) ISSUECHUNK(((uint32_t)((r + 1) & 3)) * PCH,
                                    ((uint32_t)((r + 1) % 3)) * VCH)
            if (r <= 72) {
                const uint32_t sp0  = (uint32_t)(r & 3) * PCH;
                const uint32_t sv0  = (uint32_t)(r % 3) * VCH;
                const uint32_t sq10 = (uint32_t)(r % 3) * Q1CH;
                FOR20(SSTEP)
            }
        } else if (wid == 1) {
            if (r >= 1 && r <= 73) {
                const int cu = r - 1;
                const uint32_t sp1  = (uint32_t)(cu & 3) * PCH;
                const uint32_t sv1  = (uint32_t)(cu % 3) * VCH;
                const uint32_t sq11 = (uint32_t)(cu % 3) * Q1CH;
                const uint32_t sq21 = (uint32_t)(cu & 1) * Q2CH;
                FOR20(ULOAD)
                FOR20(UCHAIN)
            }
        } else {
            if (r >= 2) {
                const int cl = r - 2;
                const uint32_t sp2  = (uint32_t)(cl & 3) * PCH;
                const uint32_t sq12 = (uint32_t)(cl % 3) * Q1CH;
                const uint32_t sq22 = (uint32_t)(cl & 1) * Q2CH;
                const int t0 = CSZ * cl;
                LSTEP(0,  t0)      LSTEP(1,  t0 + 1)  LSTEP(2,  t0 + 2)
                LSTEP(3,  t0 + 3)  LSTEP(4,  t0 + 4)  LSTEP(5,  t0 + 5)
                LSTEP(6,  t0 + 6)  LSTEP(7,  t0 + 7)  LSTEP(8,  t0 + 8)
                LSTEP(9,  t0 + 9)  LSTEP(10, t0 + 10) LSTEP(11, t0 + 11)
                LSTEP(12, t0 + 12) LSTEP(13, t0 + 13) LSTEP(14, t0 + 14)
                LSTEP(15, t0 + 15) LSTEP(16, t0 + 16) LSTEP(17, t0 + 17)
                LSTEP(18, t0 + 18) LSTEP(19, t0 + 19)
            }
        }
        __syncthreads();
    }

    if (wid == 2 && m < 4) op[1456 + m] = qk;   // t = 1456..1459

#undef FOR20
#undef ISSUECHUNK
#undef SSTEP
#undef ULOAD
#undef UCHAIN
#undef LSTEP
}

// ---------------------------------------------------------------------------
// Fallback (proven round-2 kernel, f32, no workspace) if ws too small.
// ---------------------------------------------------------------------------
#define CS 10
#define NCHUNK 146
#define IST 66

__device__ __forceinline__ float lane0f(float x) {
    return __int_as_float(__builtin_amdgcn_readlane(__float_as_int(x), 0));
}

__global__ __launch_bounds__(256, 1) void shm_pc_kernel(
    const float* __restrict__ xc, const float* __restrict__ lo,
    float* __restrict__ out)
{
    __shared__ float pbuf[2][CS][8][IST];
    __shared__ float bbuf[2][CS][4][4];

    const int lane  = threadIdx.x & 63;
    const int wid   = threadIdx.x >> 6;
    const int bbase = blockIdx.x * 4;

    const int ip = lane >> 3;
    const float A  = (ip==1)?10.f : (ip==2)?20.f : (ip==3)?1.f :
                     (ip==5)?1.f  : (ip==6)?1.f  : (ip==7)?10.f : 0.f;
    const float Bc = (ip==0)?10.f : (ip==1)?50.f : (ip==2)?680.f : (ip==3)?5.f :
                     (ip==4)?1.f  : (ip==5)?19.f : (ip==6)?99.f  : 990.f;
    const bool drcp = (ip >= 5);
    const bool dsm  = (ip == 0);
    const int  mm   = (2*lane) & 15;

    auto produce = [&](int cc, int buf) {
        const int t0 = cc * CS;
        float2 raw[14];
        float xr0[14], xr1[14], xr2[14];
#pragma unroll
        for (int r = 0; r < 14; ++r) {
            const int tau = (wid - 1) + 3 * r;
            if (tau < 40) {
                const int g  = tau / CS;
                const int tl = tau - g * CS;
                const size_t rowoff = (size_t)(bbase + g) * T_LEN + (t0 + tl);
                raw[r] = *(const float2*)(lo + rowoff * 128 + 2 * lane);
                if (lane == 0) {
                    const float* xp = xc + rowoff * 3;
                    xr0[r] = xp[0]; xr1[r] = xp[1]; xr2[r] = xp[2];
                }
            }
        }
#pragma unroll
        for (int r = 0; r < 14; ++r) {
            const int tau = (wid - 1) + 3 * r;
            if (tau < 40) {
                const int g  = tau / CS;
                const int tl = tau - g * CS;
                const float prec = lane0f(xr0[r]);
                const float pet  = lane0f(xr1[r]);
                const float temp = lane0f(xr2[r]);
                const bool frozen = (temp < 0.f);
                const float tpos = frozen ? 0.f : temp;
                const float sn   = frozen ? prec : 0.f;
                const float lpq  = frozen ? 0.f : prec;
                const float et09 = 0.9f * pet;

                float v0 = fmaf(sigmf(raw[r].x), Bc, A);
                float v1 = fmaf(sigmf(raw[r].y), Bc, A);
                v0 = drcp ? rcpf(v0) : v0;
                v1 = drcp ? rcpf(v1) : v1;
                v0 = dsm ? v0 * tpos : v0;
                v1 = dsm ? v1 * tpos : v1;

                float* dst = &pbuf[buf][tl][ip][g * 16 + mm];
                *(float2*)dst = make_float2(v0, v1);
                if (lane == 0)
                    *(float4*)&bbuf[buf][tl][g][0] = make_float4(sn, lpq, et09, 0.f);
            }
        }
    };

    const int g = lane >> 4, m = lane & 15;
    float ss = 0.f, sf = 1.f, su = 5.f, si = 10.f, sb = 15.f;
    float* op = out + (size_t)(bbase + g) * T_LEN;

    if (wid != 0) produce(0, 0);
    __syncthreads();

    for (int c = 0; c < NCHUNK; ++c) {
        if (wid == 0) {
            const int buf = c & 1;
#pragma unroll
            for (int tl = 0; tl < CS; ++tl) {
                const float* rec = &pbuf[buf][tl][0][lane];
                const float sm    = rec[0 * IST];
                const float f_thr = rec[1 * IST];
                const float sumax = rec[2 * IST];
                const float beta  = rec[3 * IST];
                const float perc  = rec[4 * IST];
                const float rkf   = rec[5 * IST];
                const float rki   = rec[6 * IST];
                const float rkb   = rec[7 * IST];
                const float4 bx = *(const float4*)&bbuf[buf][tl][g][0];

                float qs_out = fminf(ss, sm);
                ss = ss - qs_out + bx.x;
                float qsp = qs_out + bx.y;
                float qf_in = fmaxf(0.f, qsp - f_thr);
                float qu_in = fminf(qsp, f_thr);
                sf += qf_in;
                float qf_out = sf * rkf;
                sf -= qf_out;
                float inv_sumax = rcpf(sumax);
                float u = su * inv_sumax;
                float psi = __builtin_amdgcn_exp2f(beta * __builtin_amdgcn_logf(u));
                float su_temp = fmaf(qu_in, 1.f - psi, su);
                su = fminf(su_temp, sumax);
                float ovf = fmaxf(0.f, su_temp - sumax);
                float qu_out = fmaf(qu_in, psi, ovf);
                float pwp = 0.8f * sumax;
                float ktheta = (su <= pwp) ? su * inv_sumax : 1.f;
                float ret = bx.z * ktheta;
                su = fmaxf(0.f, su - ret);
                float qi_in = qu_out * perc;
                si += qi_in;
                float qi_out = si * rki;
                si -= qi_out;
                float qb_in = qu_out - qi_in;
                sb += qb_in;
                float qb_out = sb * rkb;
                sb -= qb_out;

                float q = row_sum16(qf_out + qi_out + qb_out) * 0.0625f;
                if (m == 0) op[c * CS + tl] = q;
            }
        } else if (c + 1 < NCHUNK) {
            produce(c + 1, (c + 1) & 1);
        }
        __syncthreads();
    }
}

extern "C" void kernel_launch(void* const* d_in, const int* in_sizes, int n_in,
                              void* d_out, int out_size, void* d_ws, size_t ws_size,
                              hipStream_t stream) {
    const float* xc = (const float*)d_in[0];   // [256,1460,3]
    const float* lo = (const float*)d_in[1];   // [256,1460,128]
    float* out = (float*)d_out;                // [256,1460,1]

    const size_t R2_BYTES = (size_t)NREC * 16;  // 4 planes x NREC x 4B
    const size_t V_BYTES  = (size_t)NBT * 16;   //  5,980,160

    if (ws_size >= R2_BYTES + V_BYTES) {
        uint32_t* R2 = (uint32_t*)d_ws;
        float* V = (float*)((char*)d_ws + R2_BYTES);
        shm_param_kernel<<<dim3(NREC / 256), dim3(256), 0, stream>>>(xc, lo, R2, V);
        shm_serial_kernel<<<dim3(64), dim3(192), 0, stream>>>(
            (const char*)R2, (const char*)V, out);
    } else {
        shm_pc_kernel<<<dim3(64), dim3(256), 0, stream>>>(xc, lo, out);
    }
}

// Round 23
// 147.864 us; speedup vs baseline: 1.0987x; 1.0987x over previous
//
#include <hip/hip_runtime.h>
#include <hip/hip_fp16.h>
#include <stdint.h>

#define T_LEN 1460
#define NBT (256 * T_LEN)          // 373,760 (b,t) records
#define NREC (NBT * 16)            // 5,980,160 chain records
#define CSZ 20                     // steps per chunk; 1460 = 73 * 20
#define PCH (CSZ * 1024)           // param chunk: 20 x 1024B (planar per step)
#define VCH (CSZ * 64)             // V chunk: 20 x 4 basins x 16B = 1280
#define Q1CH (CSZ * 512)           // {qf,qu} chunk: 20 x 64 x 8B = 10240
#define Q2CH (CSZ * 256)           // qu_out chunk: 20 x 64 x 4B = 5120

typedef __attribute__((address_space(3))) char lds_c;
typedef __attribute__((address_space(1))) const char g_c;

__device__ __forceinline__ float sigmf(float x) {
    float e = __builtin_amdgcn_exp2f(-1.44269504f * x);
    return __builtin_amdgcn_rcpf(1.0f + e);
}
__device__ __forceinline__ float rcpf(float x) { return __builtin_amdgcn_rcpf(x); }

__device__ __forceinline__ uint32_t pkh2(float a, float b) {
    __half2 h = __floats2half2_rn(a, b);
    union { __half2 h; uint32_t u; } c; c.h = h; return c.u;
}
__device__ __forceinline__ float2 h2f(uint32_t u) {
    union { uint32_t u; __half2 h; } c; c.u = u;
    return __half22float2(c.h);
}

// sum over each 16-lane row via full-rate DPP adds; result broadcast
__device__ __forceinline__ float row_sum16(float x) {
    x += __int_as_float(__builtin_amdgcn_update_dpp(0, __float_as_int(x), 0xB1, 0xF, 0xF, true));
    x += __int_as_float(__builtin_amdgcn_update_dpp(0, __float_as_int(x), 0x4E, 0xF, 0xF, true));
    x += __int_as_float(__builtin_amdgcn_update_dpp(0, __float_as_int(x), 0x141, 0xF, 0xF, true));
    x += __int_as_float(__builtin_amdgcn_update_dpp(0, __float_as_int(x), 0x140, 0xF, 0xF, true));
    return x;
}

// ---------------------------------------------------------------------------
// Kernel A: f16 param mapping, PRE-SWIZZLED planar-per-step output.
// Record for (group g, t) = 1024B: [p0: 64 u32][p1][p2][p3], chain-minor
// (chain = (b&3)*16 + m). Consumer lane L==chain L: plane read at +p*256+4L.
// V per (b,t): float4 {sn, lpq, 0.9*pet, 0}.
// ---------------------------------------------------------------------------
__global__ __launch_bounds__(256) void shm_param_kernel(
    const float* __restrict__ xc, const float* __restrict__ lo,
    uint32_t* __restrict__ R3, float* __restrict__ V)
{
    const int tid = blockIdx.x * 256 + threadIdx.x;
    const int m  = tid & 15;
    const int bt = tid >> 4;
    const int b  = bt / T_LEN;
    const int t  = bt - b * T_LEN;
    const int g  = b >> 2;
    const int chain = ((b & 3) << 4) | m;

    const float* lr = lo + (size_t)bt * 128 + m;
    const float r0 = lr[0],   r1 = lr[16],  r2 = lr[32],  r3 = lr[48];
    const float r4 = lr[64],  r5 = lr[80],  r6 = lr[96],  r7 = lr[112];

    const float* xp = xc + (size_t)bt * 3;
    const float prec = xp[0], pet = xp[1], temp = xp[2];
    const bool frozen = (temp < 0.f);
    const float tpos = frozen ? 0.f : temp;

    const float dd    = 10.f * sigmf(r0);
    const float sm    = tpos * dd;
    const float f_thr = fmaf(sigmf(r1), 50.f, 10.f);
    const float sumax = fmaf(sigmf(r2), 680.f, 20.f);
    const float beta  = fmaf(sigmf(r3), 5.f, 1.f);
    const float perc  = sigmf(r4);
    const float rkf   = rcpf(fmaf(sigmf(r5), 19.f, 1.f));
    const float rki   = rcpf(fmaf(sigmf(r6), 99.f, 1.f));
    const float rkb   = rcpf(fmaf(sigmf(r7), 990.f, 10.f));

    const size_t base = ((size_t)(g * T_LEN + t)) << 8;   // u32 units
    R3[base + chain]       = pkh2(sm, f_thr);
    R3[base + 64 + chain]  = pkh2(sumax, beta);
    R3[base + 128 + chain] = pkh2(perc, rkf);
    R3[base + 192 + chain] = pkh2(rki, rkb);
    if (m == 0)
        *(float4*)(V + (size_t)bt * 4) =
            make_float4(frozen ? prec : 0.f, frozen ? 0.f : prec, 0.9f * pet, 0.f);
}

// ---------------------------------------------------------------------------
// Kernel B: 3-stage wave pipeline (r21 structure), DMA16 + conflict-free LDS.
//   w0: ss-chain chunk r -> q1{qf,qu}; + DMA issuing (chunk r+1: 20 DMA16 + 2 V)
//   w1: su-chain chunk r-1: ULOAD (conflict-free b32) then register-only chain
//   w2: linear reservoirs + 16-mean + store, chunk r-2
// Rings identical to r21/r22 (passed): pring ring-4, vring/q1 ring-3, q2 ring-2.
// ---------------------------------------------------------------------------
__global__ __launch_bounds__(192, 1) void shm_serial_kernel(
    const char* __restrict__ R3,
    const char* __restrict__ V,
    float* __restrict__ out)
{
    __shared__ __align__(16) char pring[4 * PCH];    // 81920
    __shared__ __align__(16) char vring[3 * VCH];    //  3840
    __shared__ __align__(16) char q1[3 * Q1CH];      // 30720
    __shared__ __align__(16) char q2[2 * Q2CH];      // 10240

    const int lane = threadIdx.x & 63;
    const int wid  = threadIdx.x >> 6;
    const int m = lane & 15;
    const int bbase = blockIdx.x * 4;
    const int b = bbase + (lane >> 4);
    float* op = out + (size_t)b * T_LEN;

    lds_c* plp = (lds_c*)pring;
    lds_c* plv = (lds_c*)vring;
    const int voff = (lane >> 4) << 4;   // basin offset within V step-record

    // per-wave state
    float ss = 0.f;                       // w0
    float su = 5.f;                       // w1
    float sf = 1.f, si = 10.f, sb = 15.f, qk = 0.f;   // w2

    // DMA source pointers (w0): pre-swizzled records, linear lane*16
    const char* pRd = R3 + (((size_t)blockIdx.x * T_LEN) << 10) + lane * 16;
    const char* pV1 = V + ((size_t)(bbase + (lane & 3)) * T_LEN + (lane >> 2)) * 16;
    const char* pV2 = V + ((size_t)(bbase + (lane & 3)) * T_LEN + 16 + (lane >> 2)) * 16;

#define FOR20(X) X(0) X(1) X(2) X(3) X(4) X(5) X(6) X(7) X(8) X(9) \
                 X(10) X(11) X(12) X(13) X(14) X(15) X(16) X(17) X(18) X(19)

#define ISSUECHUNK(wbp, wbv) {                                                \
    _Pragma("unroll") for (int J = 0; J < 20; ++J) {                          \
        __builtin_amdgcn_global_load_lds((g_c*)(pRd + J * 1024),              \
                                         plp + (wbp) + J * 1024, 16, 0, 0);   \
    }                                                                         \
    __builtin_amdgcn_global_load_lds((g_c*)pV1, plv + (wbv), 16, 0, 0);       \
    if (lane < 16)                                                            \
        __builtin_amdgcn_global_load_lds((g_c*)pV2, plv + (wbv) + 1024, 16, 0, 0); \
    pRd += 20480; pV1 += 320; pV2 += 320; }

// w0: ss-chain step (chunk r); plane0 read at lane*4 (conflict-free)
#define SSTEP(J) {                                                            \
    const float2 p0 = h2f(*(const uint32_t*)(pring + sp0 + (J) * 1024 + lane * 4)); \
    const float2 snl = *(const float2*)(vring + sv0 + (J) * 64 + voff);       \
    const float qs_out = fminf(ss, p0.x);                                     \
    ss = (ss - qs_out) + snl.x;                                               \
    const float qsp = qs_out + snl.y;                                         \
    const float qf_ = fmaxf(0.f, qsp - p0.y);                                 \
    const float qu_ = fminf(qsp, p0.y);                                       \
    *(float2*)(q1 + sq10 + (J) * 512 + lane * 8) = make_float2(qf_, qu_); }

// w1: load phase (all independent, conflict-free b32)
#define ULOAD(J)                                                              \
    const uint32_t UY##J = *(const uint32_t*)(pring + sp1 + (J) * 1024 + 256 + lane * 4); \
    const float UE##J = *(const float*)(vring + sv1 + (J) * 64 + voff + 8);   \
    const float UQ##J = *(const float*)(q1 + sq11 + (J) * 512 + lane * 8 + 4);

// w1: register-only su-chain step (micro-optimized)
#define UCHAIN(J) {                                                           \
    const float2 p1 = h2f(UY##J);         /* sumax, beta */                   \
    const float sumax = p1.x, beta = p1.y, et09 = UE##J, qu_in = UQ##J;       \
    const float inv = rcpf(sumax);                                            \
    const float pwp = 0.8f * sumax;                                           \
    const float k1 = 1.f - et09 * inv;                                        \
    const float spq = su + qu_in;                                             \
    const float u = su * inv;                                                 \
    const float psi = __builtin_amdgcn_exp2f(beta * __builtin_amdgcn_logf(u));\
    const float su_t = fmaf(-qu_in, psi, spq);                                \
    const float su2 = fminf(su_t, sumax);                                     \
    const float ovf = fmaxf(0.f, su_t - sumax);                               \
    const float qu_out = fmaf(qu_in, psi, ovf);                               \
    const float a_ = su2 * k1;                                                \
    const float b_ = su2 - et09;                                              \
    su = fmaxf(0.f, (su2 <= pwp) ? a_ : b_);                                  \
    *(float*)(q2 + sq21 + (J) * 256 + lane * 4) = qu_out; }

// w2: linear step (chunk r-2); planes 2,3 at lane*4 (conflict-free)
#define LSTEP(J, tt) {                                                        \
    const float2 p2 = h2f(*(const uint32_t*)(pring + sp2 + (J) * 1024 + 512 + lane * 4)); \
    const float2 p3 = h2f(*(const uint32_t*)(pring + sp2 + (J) * 1024 + 768 + lane * 4)); \
    const float qf_in = *(const float*)(q1 + sq12 + (J) * 512 + lane * 8);    \
    const float quo = *(const float*)(q2 + sq22 + (J) * 256 + lane * 4);      \
    sf += qf_in; const float qf_out = sf * p2.y; sf -= qf_out;                \
    const float qi_in = quo * p2.x;                                           \
    si += qi_in; const float qi_out = si * p3.x; si -= qi_out;                \
    sb += (quo - qi_in); const float qb_out = sb * p3.y; sb -= qb_out;        \
    const float q_ = row_sum16(qf_out + qi_out + qb_out) * 0.0625f;           \
    qk = (m == ((tt) & 15)) ? q_ : qk;                                        \
    if (((tt) & 15) == 15) op[((tt) & ~15) + m] = qk; }

    // prologue: w0 issues chunk 0 into slot 0
    if (wid == 0) ISSUECHUNK(0, 0)
    __syncthreads();

    for (int r = 0; r <= 74; ++r) {
        if (wid == 0) {
            if (r <= 71) ISSUECHUNK(((uint32_t)((r + 1) & 3)) * PCH,
                                    ((uint32_t)((r + 1) % 3)) * VCH)
            if (r <= 72) {
                const uint32_t sp0  = (uint32_t)(r & 3) * PCH;
                const uint32_t sv0  = (uint32_t)(r % 3) * VCH;
                const uint32_t sq10 = (uint32_t)(r % 3) * Q1CH;
                FOR20(SSTEP)
            }
        } else if (wid == 1) {
            if (r >= 1 && r <= 73) {
                const int cu = r - 1;
                const uint32_t sp1  = (uint32_t)(cu & 3) * PCH;
                const uint32_t sv1  = (uint32_t)(cu % 3) * VCH;
                const uint32_t sq11 = (uint32_t)(cu % 3) * Q1CH;
                const uint32_t sq21 = (uint32_t)(cu & 1) * Q2CH;
                FOR20(ULOAD)
                FOR20(UCHAIN)
            }
        } else {
            if (r >= 2) {
                const int cl = r - 2;
                const uint32_t sp2  = (uint32_t)(cl & 3) * PCH;
                const uint32_t sq12 = (uint32_t)(cl % 3) * Q1CH;
                const uint32_t sq22 = (uint32_t)(cl & 1) * Q2CH;
                const int t0 = CSZ * cl;
                LSTEP(0,  t0)      LSTEP(1,  t0 + 1)  LSTEP(2,  t0 + 2)
                LSTEP(3,  t0 + 3)  LSTEP(4,  t0 + 4)  LSTEP(5,  t0 + 5)
                LSTEP(6,  t0 + 6)  LSTEP(7,  t0 + 7)  LSTEP(8,  t0 + 8)
                LSTEP(9,  t0 + 9)  LSTEP(10, t0 + 10) LSTEP(11, t0 + 11)
                LSTEP(12, t0 + 12) LSTEP(13, t0 + 13) LSTEP(14, t0 + 14)
                LSTEP(15, t0 + 15) LSTEP(16, t0 + 16) LSTEP(17, t0 + 17)
                LSTEP(18, t0 + 18) LSTEP(19, t0 + 19)
            }
        }
        __syncthreads();
    }

    if (wid == 2 && m < 4) op[1456 + m] = qk;   // t = 1456..1459

#undef FOR20
#undef ISSUECHUNK
#undef SSTEP
#undef ULOAD
#undef UCHAIN
#undef LSTEP
}

// ---------------------------------------------------------------------------
// Fallback (proven round-2 kernel, f32, no workspace) if ws too small.
// ---------------------------------------------------------------------------
#define CS 10
#define NCHUNK 146
#define IST 66

__device__ __forceinline__ float lane0f(float x) {
    return __int_as_float(__builtin_amdgcn_readlane(__float_as_int(x), 0));
}

__global__ __launch_bounds__(256, 1) void shm_pc_kernel(
    const float* __restrict__ xc, const float* __restrict__ lo,
    float* __restrict__ out)
{
    __shared__ float pbuf[2][CS][8][IST];
    __shared__ float bbuf[2][CS][4][4];

    const int lane  = threadIdx.x & 63;
    const int wid   = threadIdx.x >> 6;
    const int bbase = blockIdx.x * 4;

    const int ip = lane >> 3;
    const float A  = (ip==1)?10.f : (ip==2)?20.f : (ip==3)?1.f :
                     (ip==5)?1.f  : (ip==6)?1.f  : (ip==7)?10.f : 0.f;
    const float Bc = (ip==0)?10.f : (ip==1)?50.f : (ip==2)?680.f : (ip==3)?5.f :
                     (ip==4)?1.f  : (ip==5)?19.f : (ip==6)?99.f  : 990.f;
    const bool drcp = (ip >= 5);
    const bool dsm  = (ip == 0);
    const int  mm   = (2*lane) & 15;

    auto produce = [&](int cc, int buf) {
        const int t0 = cc * CS;
        float2 raw[14];
        float xr0[14], xr1[14], xr2[14];
#pragma unroll
        for (int r = 0; r < 14; ++r) {
            const int tau = (wid - 1) + 3 * r;
            if (tau < 40) {
                const int g  = tau / CS;
                const int tl = tau - g * CS;
                const size_t rowoff = (size_t)(bbase + g) * T_LEN + (t0 + tl);
                raw[r] = *(const float2*)(lo + rowoff * 128 + 2 * lane);
                if (lane == 0) {
                    const float* xp = xc + rowoff * 3;
                    xr0[r] = xp[0]; xr1[r] = xp[1]; xr2[r] = xp[2];
                }
            }
        }
#pragma unroll
        for (int r = 0; r < 14; ++r) {
            const int tau = (wid - 1) + 3 * r;
            if (tau < 40) {
                const int g  = tau / CS;
                const int tl = tau - g * CS;
                const float prec = lane0f(xr0[r]);
                const float pet  = lane0f(xr1[r]);
                const float temp = lane0f(xr2[r]);
                const bool frozen = (temp < 0.f);
                const float tpos = frozen ? 0.f : temp;
                const float sn   = frozen ? prec : 0.f;
                const float lpq  = frozen ? 0.f : prec;
                const float et09 = 0.9f * pet;

                float v0 = fmaf(sigmf(raw[r].x), Bc, A);
                float v1 = fmaf(sigmf(raw[r].y), Bc, A);
                v0 = drcp ? rcpf(v0) : v0;
                v1 = drcp ? rcpf(v1) : v1;
                v0 = dsm ? v0 * tpos : v0;
                v1 = dsm ? v1 * tpos : v1;

                float* dst = &pbuf[buf][tl][ip][g * 16 + mm];
                *(float2*)dst = make_float2(v0, v1);
                if (lane == 0)
                    *(float4*)&bbuf[buf][tl][g][0] = make_float4(sn, lpq, et09, 0.f);
            }
        }
    };

    const int g = lane >> 4, m = lane & 15;
    float ss = 0.f, sf = 1.f, su = 5.f, si = 10.f, sb = 15.f;
    float* op = out + (size_t)(bbase + g) * T_LEN;

    if (wid != 0) produce(0, 0);
    __syncthreads();

    for (int c = 0; c < NCHUNK; ++c) {
        if (wid == 0) {
            const int buf = c & 1;
#pragma unroll
            for (int tl = 0; tl < CS; ++tl) {
                const float* rec = &pbuf[buf][tl][0][lane];
                const float sm    = rec[0 * IST];
                const float f_thr = rec[1 * IST];
                const float sumax = rec[2 * IST];
                const float beta  = rec[3 * IST];
                const float perc  = rec[4 * IST];
                const float rkf   = rec[5 * IST];
                const float rki   = rec[6 * IST];
                const float rkb   = rec[7 * IST];
                const float4 bx = *(const float4*)&bbuf[buf][tl][g][0];

                float qs_out = fminf(ss, sm);
                ss = ss - qs_out + bx.x;
                float qsp = qs_out + bx.y;
                float qf_in = fmaxf(0.f, qsp - f_thr);
                float qu_in = fminf(qsp, f_thr);
                sf += qf_in;
                float qf_out = sf * rkf;
                sf -= qf_out;
                float inv_sumax = rcpf(sumax);
                float u = su * inv_sumax;
                float psi = __builtin_amdgcn_exp2f(beta * __builtin_amdgcn_logf(u));
                float su_temp = fmaf(qu_in, 1.f - psi, su);
                su = fminf(su_temp, sumax);
                float ovf = fmaxf(0.f, su_temp - sumax);
                float qu_out = fmaf(qu_in, psi, ovf);
                float pwp = 0.8f * sumax;
                float ktheta = (su <= pwp) ? su * inv_sumax : 1.f;
                float ret = bx.z * ktheta;
                su = fmaxf(0.f, su - ret);
                float qi_in = qu_out * perc;
                si += qi_in;
                float qi_out = si * rki;
                si -= qi_out;
                float qb_in = qu_out - qi_in;
                sb += qb_in;
                float qb_out = sb * rkb;
                sb -= qb_out;

                float q = row_sum16(qf_out + qi_out + qb_out) * 0.0625f;
                if (m == 0) op[c * CS + tl] = q;
            }
        } else if (c + 1 < NCHUNK) {
            produce(c + 1, (c + 1) & 1);
        }
        __syncthreads();
    }
}

extern "C" void kernel_launch(void* const* d_in, const int* in_sizes, int n_in,
                              void* d_out, int out_size, void* d_ws, size_t ws_size,
                              hipStream_t stream) {
    const float* xc = (const float*)d_in[0];   // [256,1460,3]
    const float* lo = (const float*)d_in[1];   // [256,1460,128]
    float* out = (float*)d_out;                // [256,1460,1]

    const size_t R3_BYTES = (size_t)NREC * 16; // 64 groups x 1460 x 1024B
    const size_t V_BYTES  = (size_t)NBT * 16;  //  5,980,160

    if (ws_size >= R3_BYTES + V_BYTES) {
        uint32_t* R3 = (uint32_t*)d_ws;
        float* V = (float*)((char*)d_ws + R3_BYTES);
        shm_param_kernel<<<dim3(NREC / 256), dim3(256), 0, stream>>>(xc, lo, R3, V);
        shm_serial_kernel<<<dim3(64), dim3(192), 0, stream>>>(
            (const char*)R3, (const char*)V, out);
    } else {
        shm_pc_kernel<<<dim3(64), dim3(256), 0, stream>>>(xc, lo, out);
    }
}